// Round 15
// baseline (726.889 us; speedup 1.0000x reference)
//
#include <hip/hip_runtime.h>

#define B_ 256
#define T_ 2048
#define H_ 64

typedef float f32x4 __attribute__((ext_vector_type(4)));
typedef _Float16 h16x2 __attribute__((ext_vector_type(2)));
typedef _Float16 h16x8 __attribute__((ext_vector_type(8)));

__device__ __forceinline__ float fdot2(h16x2 a, h16x2 b, float c) {
#if __has_builtin(__builtin_amdgcn_fdot2)
    return __builtin_amdgcn_fdot2(a, b, c, false);   // v_dot2_f32_f16
#else
    float d;
    asm("v_dot2_f32_f16 %0, %1, %2, %3" : "=v"(d) : "v"(a), "v"(b), "v"(c));
    return d;
#endif
}

__device__ __forceinline__ float readlane_f(float v, int idx) {
    return __builtin_bit_cast(float,
        __builtin_amdgcn_readlane(__builtin_bit_cast(int, v), idx));
}

#define NLOG2E (-1.4426950408889634f)   // -log2(e): sigmoid prescale
#define TLOG2E ( 2.8853900817779268f)   // 2*log2(e): tanh prescale

// Single wave per batch row, zero barriers. DUAL-PIPE matvec:
//   k in [0,32):  VALU, 48 v_dot2_f32_f16 (lane j owns rows {j,64+j,128+j})
//   k in [32,64): MFMA pipe, 12 M=1-degenerate v_mfma_f32_16x16x32_f16
//                 (R10's hardware-verified fragment indexing, kt=1 tile)
// Ledger basis: R11/R13/R14 VALUBusy fits VOP3P at ~4cyc/wave64, so the
// 192-MAC matvec costs 384 cyc on ANY single pipe (96 dot2 = 192 fma =
// 24 MFMA -- all 384). Splitting across the two pipes halves it: MFMAs
// issue first (1 slot each, pipe runs in background), VALU dots issue
// under them, results combine ~in time. MFMA C-layout: every lane holds
// the gate value for channel 16*(lane>>4)+(lane&15) == lane -- combine
// with the VALU partial needs only a 2-level cndmask select of acc[kg].
// MFMA weights may live in AGPRs natively (no copy tax).
__global__ __launch_bounds__(64, 1)
void gru_kernel(const float* __restrict__ x,
                const float* __restrict__ W_ih,
                const float* __restrict__ W_hh,
                const float* __restrict__ b_ih,
                const float* __restrict__ b_hh,
                float* __restrict__ out)
{
    __shared__ __align__(16) _Float16 shh[H_];

    const int lane = threadIdx.x;
    const int ln15 = lane & 15;
    const int kg   = lane >> 4;
    const int b    = blockIdx.x;

    // ---- VALU weights: rows {lane,64+lane,128+lane}, k<32, prescaled f16 ----
    h16x2 wr[16], wz[16], wn[16];
    {
        const f32x4* pr = (const f32x4*)(W_hh + (size_t)lane * H_);
        const f32x4* pz = (const f32x4*)(W_hh + (size_t)(64 + lane) * H_);
        const f32x4* pn = (const f32x4*)(W_hh + (size_t)(128 + lane) * H_);
        #pragma unroll
        for (int q = 0; q < 8; ++q) {
            f32x4 vr = pr[q], vz = pz[q], vn = pn[q];
            wr[2*q]   = h16x2{(_Float16)(NLOG2E * vr.x), (_Float16)(NLOG2E * vr.y)};
            wr[2*q+1] = h16x2{(_Float16)(NLOG2E * vr.z), (_Float16)(NLOG2E * vr.w)};
            wz[2*q]   = h16x2{(_Float16)(NLOG2E * vz.x), (_Float16)(NLOG2E * vz.y)};
            wz[2*q+1] = h16x2{(_Float16)(NLOG2E * vz.z), (_Float16)(NLOG2E * vz.w)};
            wn[2*q]   = h16x2{(_Float16)(TLOG2E * vn.x), (_Float16)(TLOG2E * vn.y)};
            wn[2*q+1] = h16x2{(_Float16)(TLOG2E * vn.z), (_Float16)(TLOG2E * vn.w)};
        }
    }
    #pragma unroll
    for (int i = 0; i < 16; ++i)
        asm volatile("" : "+v"(wr[i]), "+v"(wz[i]), "+v"(wn[i]));

    // ---- MFMA weights (k>=32): R10's verified B-fragment, kt=1 ----
    h16x8 wbm[3][4];
    #pragma unroll
    for (int g = 0; g < 3; ++g) {
        const float s = (g == 2) ? TLOG2E : NLOG2E;
        #pragma unroll
        for (int nt = 0; nt < 4; ++nt) {
            const float* p = W_hh + (size_t)(g * 64 + nt * 16 + ln15) * H_
                           + 32 + 8 * kg;
            h16x8 v;
            #pragma unroll
            for (int j = 0; j < 8; ++j) v[j] = (_Float16)(s * p[j]);
            wbm[g][nt] = v;
        }
    }
    #pragma unroll
    for (int g = 0; g < 3; ++g)
        #pragma unroll
        for (int nt = 0; nt < 4; ++nt)
            asm volatile("" : "+v"(wbm[g][nt]));

    // x-side params, prescaled
    const float wihr = NLOG2E * W_ih[lane];
    const float wihz = NLOG2E * W_ih[64 + lane];
    const float wihn = TLOG2E * W_ih[128 + lane];
    const float br   = NLOG2E * (b_ih[lane]      + b_hh[lane]);
    const float bz   = NLOG2E * (b_ih[64 + lane] + b_hh[64 + lane]);
    const float bhn  = TLOG2E * b_hh[128 + lane];
    const float bin  = TLOG2E * b_ih[128 + lane];

    const float* __restrict__ xrow = x + (size_t)b * T_;
    float* __restrict__ orow = out + (size_t)b * T_;

    shh[lane] = (_Float16)0.0f;      // h0 = 0 (single wave: in-order LDS)

    float h_own = 0.0f;
    float oval  = 0.0f;
    float xa = xrow[lane];
    float xb = 0.0f;
    const f32x4 z4 = {0.f, 0.f, 0.f, 0.f};
    const bool kb0 = (kg & 1) != 0;
    const bool kb1 = (kg & 2) != 0;

    for (int tb = 0; tb < T_ / 64; ++tb) {
        if (tb < T_ / 64 - 1) xb = xrow[(tb + 1) * 64 + lane];

        #pragma unroll 4
        for (int t2 = 0; t2 < 64; ++t2) {
            const float xt  = readlane_f(xa, t2);
            const float xpr = fmaf(xt, wihr, br);
            const float xpz = fmaf(xt, wihz, bz);
            const float xpn = fmaf(xt, wihn, bin);

            // ---- LDS reads: a1 (MFMA A, k>=32) + hh (VALU, k<32) ----
            h16x8 a1 = *(const h16x8*)&shh[32 + 8 * kg];   // ds_read_b128
            h16x2 hh[16];
            const f32x4* hp = (const f32x4*)shh;
            #pragma unroll
            for (int q = 0; q < 4; ++q) {                  // 4x ds_read_b128
                union { f32x4 f; h16x2 h[4]; } u;
                u.f = hp[q];
                hh[4*q]   = u.h[0];
                hh[4*q+1] = u.h[1];
                hh[4*q+2] = u.h[2];
                hh[4*q+3] = u.h[3];
            }

            // ---- MFMA pipe: 12 independent MFMAs issued first ----
            f32x4 mr[4], mz[4], mn[4];
            #pragma unroll
            for (int nt = 0; nt < 4; ++nt)
                mr[nt] = __builtin_amdgcn_mfma_f32_16x16x32_f16(a1, wbm[0][nt], z4, 0, 0, 0);
            #pragma unroll
            for (int nt = 0; nt < 4; ++nt)
                mz[nt] = __builtin_amdgcn_mfma_f32_16x16x32_f16(a1, wbm[1][nt], z4, 0, 0, 0);
            #pragma unroll
            for (int nt = 0; nt < 4; ++nt)
                mn[nt] = __builtin_amdgcn_mfma_f32_16x16x32_f16(a1, wbm[2][nt], z4, 0, 0, 0);

            // ---- VALU pipe: r-gate dots (k<32) under the MFMAs ----
            float ar0 = 0.f, ar1 = 0.f;
            #pragma unroll
            for (int i = 0; i < 16; i += 2) {
                ar0 = fdot2(wr[i],   hh[i],   ar0);
                ar1 = fdot2(wr[i+1], hh[i+1], ar1);
            }
            // select my MFMA partial: chan lane = acc[kg], element 0
            float r01 = kb0 ? mr[1][0] : mr[0][0];
            float r23 = kb0 ? mr[3][0] : mr[2][0];
            float sr  = (ar0 + ar1) + (kb1 ? r23 : r01) + xpr;
            float r   = __builtin_amdgcn_rcpf(1.0f + __builtin_amdgcn_exp2f(sr));

            // ---- z-gate ----
            float az0 = 0.f, az1 = 0.f;
            #pragma unroll
            for (int i = 0; i < 16; i += 2) {
                az0 = fdot2(wz[i],   hh[i],   az0);
                az1 = fdot2(wz[i+1], hh[i+1], az1);
            }
            float z01 = kb0 ? mz[1][0] : mz[0][0];
            float z23 = kb0 ? mz[3][0] : mz[2][0];
            float sz  = (az0 + az1) + (kb1 ? z23 : z01) + xpz;
            float z   = __builtin_amdgcn_rcpf(1.0f + __builtin_amdgcn_exp2f(sz));

            // ---- n-gate ----
            float an0 = 0.f, an1 = 0.f;
            #pragma unroll
            for (int i = 0; i < 16; i += 2) {
                an0 = fdot2(wn[i],   hh[i],   an0);
                an1 = fdot2(wn[i+1], hh[i+1], an1);
            }
            float n01 = kb0 ? mn[1][0] : mn[0][0];
            float n23 = kb0 ? mn[3][0] : mn[2][0];
            float hn  = (an0 + an1) + (kb1 ? n23 : n01) + bhn;
            float pre = fmaf(r, hn, xpn);
            float n   = fmaf(-2.0f, __builtin_amdgcn_rcpf(
                              1.0f + __builtin_amdgcn_exp2f(pre)), 1.0f);

            float h_new = fmaf(z, h_own - n, n);   // (1-z)*n + z*h
            h_own = h_new;

            // publish FIRST: next step's read turnaround starts now
            shh[lane] = (_Float16)h_new;

            // output latch (off critical path)
            float h63 = readlane_f(h_new, 63);
            oval = (t2 == lane) ? h63 : oval;
        }

        orow[tb * 64 + lane] = oval;               // coalesced 256B store
        xa = xb;
    }
}

extern "C" void kernel_launch(void* const* d_in, const int* in_sizes, int n_in,
                              void* d_out, int out_size, void* d_ws, size_t ws_size,
                              hipStream_t stream) {
    const float* x    = (const float*)d_in[0];
    const float* W_ih = (const float*)d_in[1];
    const float* W_hh = (const float*)d_in[2];
    const float* b_ih = (const float*)d_in[3];
    const float* b_hh = (const float*)d_in[4];
    float* out = (float*)d_out;

    dim3 grid(B_), block(64);
    gru_kernel<<<grid, block, 0, stream>>>(x, W_ih, W_hh, b_ih, b_hh, out);
}

// Round 16
// 682.455 us; speedup vs baseline: 1.0651x; 1.0651x over previous
//
#include <hip/hip_runtime.h>

#define B_ 256
#define T_ 2048
#define H_ 64

typedef float f32x4 __attribute__((ext_vector_type(4)));
typedef _Float16 h16x2 __attribute__((ext_vector_type(2)));
typedef _Float16 h16x8 __attribute__((ext_vector_type(8)));

__device__ __forceinline__ float fdot2(h16x2 a, h16x2 b, float c) {
#if __has_builtin(__builtin_amdgcn_fdot2)
    return __builtin_amdgcn_fdot2(a, b, c, false);   // v_dot2_f32_f16
#else
    float d;
    asm("v_dot2_f32_f16 %0, %1, %2, %3" : "=v"(d) : "v"(a), "v"(b), "v"(c));
    return d;
#endif
}

__device__ __forceinline__ float readlane_f(float v, int idx) {
    return __builtin_bit_cast(float,
        __builtin_amdgcn_readlane(__builtin_bit_cast(int, v), idx));
}

#define NLOG2E (-1.4426950408889634f)   // -log2(e): sigmoid prescale
#define TLOG2E ( 2.8853900817779268f)   // 2*log2(e): tanh prescale

// Single wave per batch row, zero barriers. GATE-LEVEL dual-pipe split:
//   r,z gates: VALU, 64 v_dot2_f32_f16 (256 issue cyc)
//   n gate:    MFMA pipe, 8 M=1-degenerate mfma_f32_16x16x32_f16
//              (128 pipe cyc, issued FIRST, result consumed LAST -- after
//              r's dots+sigmoid and z's dots, ~280 cyc later: fully hidden)
// vs R15 (which split by K and stalled on r's MFMA partial immediately).
// Ledger: all dot primitives cost 4cyc/wave64 (R12/R13 falsified the
// copy-tax theory), so single-pipe matvec floor = 384 cyc; this split's
// VALU floor = 256 + ~90 overhead, MFMA hidden. n's 32 weight VGPRs are
// MFMA B-operands (AGPR-native, free) -> arch-VGPR demand ~125, finally
// inside the allocator's 128 comfort zone. Fragment indexing byte-identical
// to R10 (hardware-validated, passed). Output: lane 63 stashes h to LDS
// obuf[t2] (f32), wave flushes 64 coalesced once per block -- no per-step
// readlane/cndmask latch.
__global__ __launch_bounds__(64, 1)
void gru_kernel(const float* __restrict__ x,
                const float* __restrict__ W_ih,
                const float* __restrict__ W_hh,
                const float* __restrict__ b_ih,
                const float* __restrict__ b_hh,
                float* __restrict__ out)
{
    __shared__ __align__(16) _Float16 shh[H_];
    __shared__ float obuf[64];

    const int lane = threadIdx.x;
    const int ln15 = lane & 15;
    const int kg   = lane >> 4;
    const int b    = blockIdx.x;

    // ---- VALU weights: r,z rows {lane, 64+lane}, full k, prescaled f16 ----
    h16x2 wr[32], wz[32];
    {
        const f32x4* pr = (const f32x4*)(W_hh + (size_t)lane * H_);
        const f32x4* pz = (const f32x4*)(W_hh + (size_t)(64 + lane) * H_);
        #pragma unroll
        for (int q = 0; q < 16; ++q) {
            f32x4 vr = pr[q], vz = pz[q];
            wr[2*q]   = h16x2{(_Float16)(NLOG2E * vr.x), (_Float16)(NLOG2E * vr.y)};
            wr[2*q+1] = h16x2{(_Float16)(NLOG2E * vr.z), (_Float16)(NLOG2E * vr.w)};
            wz[2*q]   = h16x2{(_Float16)(NLOG2E * vz.x), (_Float16)(NLOG2E * vz.y)};
            wz[2*q+1] = h16x2{(_Float16)(NLOG2E * vz.z), (_Float16)(NLOG2E * vz.w)};
        }
    }
    #pragma unroll
    for (int i = 0; i < 32; ++i)
        asm volatile("" : "+v"(wr[i]), "+v"(wz[i]));

    // ---- MFMA weights: n gate, R10's verified B-fragments, kt=0,1 ----
    h16x8 wbn[4][2];
    #pragma unroll
    for (int nt = 0; nt < 4; ++nt) {
        #pragma unroll
        for (int kt = 0; kt < 2; ++kt) {
            const float* p = W_hh + (size_t)(2 * 64 + nt * 16 + ln15) * H_
                           + kt * 32 + 8 * kg;
            h16x8 v;
            #pragma unroll
            for (int j = 0; j < 8; ++j) v[j] = (_Float16)(TLOG2E * p[j]);
            wbn[nt][kt] = v;
        }
    }
    #pragma unroll
    for (int nt = 0; nt < 4; ++nt)
        asm volatile("" : "+v"(wbn[nt][0]), "+v"(wbn[nt][1]));

    // x-side params, prescaled
    const float wihr = NLOG2E * W_ih[lane];
    const float wihz = NLOG2E * W_ih[64 + lane];
    const float wihn = TLOG2E * W_ih[128 + lane];
    const float br   = NLOG2E * (b_ih[lane]      + b_hh[lane]);
    const float bz   = NLOG2E * (b_ih[64 + lane] + b_hh[64 + lane]);
    const float bhn  = TLOG2E * b_hh[128 + lane];
    const float bin  = TLOG2E * b_ih[128 + lane];

    const float* __restrict__ xrow = x + (size_t)b * T_;
    float* __restrict__ orow = out + (size_t)b * T_;

    shh[lane] = (_Float16)0.0f;      // h0 = 0 (single wave: in-order LDS)

    float h_own = 0.0f;
    float xa = xrow[lane];
    float xb = 0.0f;
    const f32x4 z4 = {0.f, 0.f, 0.f, 0.f};
    const bool kb0 = (kg & 1) != 0;
    const bool kb1 = (kg & 2) != 0;

    for (int tb = 0; tb < T_ / 64; ++tb) {
        if (tb < T_ / 64 - 1) xb = xrow[(tb + 1) * 64 + lane];

        #pragma unroll 4
        for (int t2 = 0; t2 < 64; ++t2) {
            const float xt  = readlane_f(xa, t2);
            const float xpr = fmaf(xt, wihr, br);
            const float xpz = fmaf(xt, wihz, bz);
            const float xpn = fmaf(xt, wihn, bin);

            // ---- LDS reads: MFMA A-frags first, then broadcast hh ----
            h16x8 a0 = *(const h16x8*)&shh[8 * kg];        // k 0..31
            h16x8 a1 = *(const h16x8*)&shh[32 + 8 * kg];   // k 32..63
            h16x2 hh[32];
            const f32x4* hp = (const f32x4*)shh;
            #pragma unroll
            for (int q = 0; q < 8; ++q) {
                union { f32x4 f; h16x2 h[4]; } u;
                u.f = hp[q];
                hh[4*q]   = u.h[0];
                hh[4*q+1] = u.h[1];
                hh[4*q+2] = u.h[2];
                hh[4*q+3] = u.h[3];
            }

            // ---- n-gate on MFMA pipe: 8 MFMAs, 4 independent 2-chains;
            //      result consumed ~280 cyc later (after r,z) -> hidden ----
            f32x4 mn[4];
            #pragma unroll
            for (int nt = 0; nt < 4; ++nt)
                mn[nt] = __builtin_amdgcn_mfma_f32_16x16x32_f16(a0, wbn[nt][0], z4, 0, 0, 0);
            #pragma unroll
            for (int nt = 0; nt < 4; ++nt)
                mn[nt] = __builtin_amdgcn_mfma_f32_16x16x32_f16(a1, wbn[nt][1], mn[nt], 0, 0, 0);

            // ---- r-gate on VALU (32 dot2, 4 chains), sigmoid first ----
            float ar[4] = {0.f, 0.f, 0.f, 0.f};
            #pragma unroll
            for (int i = 0; i < 32; ++i) ar[i & 3] = fdot2(wr[i], hh[i], ar[i & 3]);
            float sr = ((ar[0] + ar[1]) + (ar[2] + ar[3])) + xpr;
            float r  = __builtin_amdgcn_rcpf(1.0f + __builtin_amdgcn_exp2f(sr));

            // ---- z-gate on VALU ----
            float az[4] = {0.f, 0.f, 0.f, 0.f};
            #pragma unroll
            for (int i = 0; i < 32; ++i) az[i & 3] = fdot2(wz[i], hh[i], az[i & 3]);
            float sz = ((az[0] + az[1]) + (az[2] + az[3])) + xpz;
            float z  = __builtin_amdgcn_rcpf(1.0f + __builtin_amdgcn_exp2f(sz));

            // ---- n combine: my channel (= lane) lives in mn[kg][0] ----
            float n01 = kb0 ? mn[1][0] : mn[0][0];
            float n23 = kb0 ? mn[3][0] : mn[2][0];
            float hn  = (kb1 ? n23 : n01) + bhn;
            float pre = fmaf(r, hn, xpn);
            float n   = fmaf(-2.0f, __builtin_amdgcn_rcpf(
                              1.0f + __builtin_amdgcn_exp2f(pre)), 1.0f);

            float h_new = fmaf(z, h_own - n, n);   // (1-z)*n + z*h
            h_own = h_new;

            // publish FIRST: next step's read turnaround starts now
            shh[lane] = (_Float16)h_new;

            // output: lane 63 stashes (off critical path, no latch math)
            if (lane == 63) obuf[t2] = h_new;
        }

        orow[tb * 64 + lane] = obuf[lane];         // coalesced 256B store
        xa = xb;
    }
}

extern "C" void kernel_launch(void* const* d_in, const int* in_sizes, int n_in,
                              void* d_out, int out_size, void* d_ws, size_t ws_size,
                              hipStream_t stream) {
    const float* x    = (const float*)d_in[0];
    const float* W_ih = (const float*)d_in[1];
    const float* W_hh = (const float*)d_in[2];
    const float* b_ih = (const float*)d_in[3];
    const float* b_hh = (const float*)d_in[4];
    float* out = (float*)d_out;

    dim3 grid(B_), block(64);
    gru_kernel<<<grid, block, 0, stream>>>(x, W_ih, W_hh, b_ih, b_hh, out);
}

// Round 17
// 633.995 us; speedup vs baseline: 1.1465x; 1.0764x over previous
//
#include <hip/hip_runtime.h>

#define B_ 256
#define T_ 2048
#define H_ 64

typedef float f32x4 __attribute__((ext_vector_type(4)));
typedef _Float16 h16x2 __attribute__((ext_vector_type(2)));

__device__ __forceinline__ float fdot2(h16x2 a, h16x2 b, float c) {
#if __has_builtin(__builtin_amdgcn_fdot2)
    return __builtin_amdgcn_fdot2(a, b, c, false);   // v_dot2_f32_f16
#else
    float d;
    asm("v_dot2_f32_f16 %0, %1, %2, %3" : "=v"(d) : "v"(a), "v"(b), "v"(c));
    return d;
#endif
}

__device__ __forceinline__ float readlane_f(float v, int idx) {
    return __builtin_bit_cast(float,
        __builtin_amdgcn_readlane(__builtin_bit_cast(int, v), idx));
}

#define NLOG2E (-1.4426950408889634f)   // -log2(e): sigmoid prescale
#define TLOG2E ( 2.8853900817779268f)   // 2*log2(e): tanh prescale

// FINAL-CLASS KERNEL: R13 structure (best measured, 616 us) + lane-63 LDS
// output stash (R16-proven) replacing the per-step readlane/cmp/cndmask
// latch. Design summary after 16 measured variants:
//  - single wave per batch row, zero barriers (multi-wave sync costs
//    >=250 cyc/step: R1/R5/R6/R9);
//  - f16 prescaled weights resident in regs (exp2 factors folded: no mul
//    at the head of any transcendental chain);
//  - gate pre-activations via mixed pk_fma_f16 chains + fdot2 folds,
//    gate-ordered r->z->n so each sigmoid's latency hides under the next
//    gate's dot issue;
//  - h exchanged through a 128-byte LDS broadcast image (8 ds_read_b128,
//    uniform addr, conflict-free; publish immediately after h_new);
//  - MFMA rejected: single-wave MFMA ~16 cyc/instr effective (R10), and
//    in-wave MFMA/VALU overlap does not materialize (R15/R16).
__global__ __launch_bounds__(64, 1)
void gru_kernel(const float* __restrict__ x,
                const float* __restrict__ W_ih,
                const float* __restrict__ W_hh,
                const float* __restrict__ b_ih,
                const float* __restrict__ b_hh,
                float* __restrict__ out)
{
#pragma clang fp contract(fast)
    __shared__ __align__(16) _Float16 shh[H_];
    __shared__ float obuf[64];

    const int lane = threadIdx.x;
    const int b    = blockIdx.x;

    // ---- preload W_hh rows {lane, 64+lane, 128+lane}, prescale, cvt f16 ----
    h16x2 wr[32], wz[32], wn[32];
    {
        const f32x4* pr = (const f32x4*)(W_hh + (size_t)lane * H_);
        const f32x4* pz = (const f32x4*)(W_hh + (size_t)(64 + lane) * H_);
        const f32x4* pn = (const f32x4*)(W_hh + (size_t)(128 + lane) * H_);
        #pragma unroll
        for (int q = 0; q < 16; ++q) {
            f32x4 vr = pr[q], vz = pz[q], vn = pn[q];
            wr[2*q]   = h16x2{(_Float16)(NLOG2E * vr.x), (_Float16)(NLOG2E * vr.y)};
            wr[2*q+1] = h16x2{(_Float16)(NLOG2E * vr.z), (_Float16)(NLOG2E * vr.w)};
            wz[2*q]   = h16x2{(_Float16)(NLOG2E * vz.x), (_Float16)(NLOG2E * vz.y)};
            wz[2*q+1] = h16x2{(_Float16)(NLOG2E * vz.z), (_Float16)(NLOG2E * vz.w)};
            wn[2*q]   = h16x2{(_Float16)(TLOG2E * vn.x), (_Float16)(TLOG2E * vn.y)};
            wn[2*q+1] = h16x2{(_Float16)(TLOG2E * vn.z), (_Float16)(TLOG2E * vn.w)};
        }
    }
    #pragma unroll
    for (int i = 0; i < 32; ++i)
        asm volatile("" : "+v"(wr[i]), "+v"(wz[i]), "+v"(wn[i]));

    // x-side params, prescaled
    const float wihr = NLOG2E * W_ih[lane];
    const float wihz = NLOG2E * W_ih[64 + lane];
    const float wihn = TLOG2E * W_ih[128 + lane];
    const float br   = NLOG2E * (b_ih[lane]      + b_hh[lane]);
    const float bz   = NLOG2E * (b_ih[64 + lane] + b_hh[64 + lane]);
    const float bhn  = TLOG2E * b_hh[128 + lane];
    const float bin  = TLOG2E * b_ih[128 + lane];

    const h16x2 ones = h16x2{(_Float16)1.0f, (_Float16)1.0f};

    const float* __restrict__ xrow = x + (size_t)b * T_;
    float* __restrict__ orow = out + (size_t)b * T_;

    shh[lane] = (_Float16)0.0f;      // h0 = 0 (single wave: in-order LDS)

    float h_own = 0.0f;
    float xa = xrow[lane];           // current 64-step block of x
    float xb = 0.0f;

    for (int tb = 0; tb < T_ / 64; ++tb) {
        if (tb < T_ / 64 - 1) xb = xrow[(tb + 1) * 64 + lane];

        #pragma unroll 4
        for (int t2 = 0; t2 < 64; ++t2) {
            const float xt  = readlane_f(xa, t2);
            const float xpr = fmaf(xt, wihr, br);
            const float xpz = fmaf(xt, wihz, bz);
            const float xpn = fmaf(xt, wihn, bin);

            // ---- h: 8 broadcast ds_read_b128 (64 f16 = 128 B) ----
            h16x2 hh[32];
            const f32x4* hp = (const f32x4*)shh;
            #pragma unroll
            for (int q = 0; q < 8; ++q) {
                union { f32x4 f; h16x2 h[4]; } u;
                u.f = hp[q];
                hh[4*q]   = u.h[0];
                hh[4*q+1] = u.h[1];
                hh[4*q+2] = u.h[2];
                hh[4*q+3] = u.h[3];
            }

            // ---- r-gate: 32 pk_fma_f16 (4 chains of 8) + 4 fdot2 fold ----
            h16x2 cr[4] = {h16x2{0,0}, h16x2{0,0}, h16x2{0,0}, h16x2{0,0}};
            #pragma unroll
            for (int i = 0; i < 32; ++i) cr[i >> 3] = wr[i] * hh[i] + cr[i >> 3];
            float sr = xpr;
            #pragma unroll
            for (int k = 0; k < 4; ++k) sr = fdot2(cr[k], ones, sr);
            float r  = __builtin_amdgcn_rcpf(1.0f + __builtin_amdgcn_exp2f(sr));

            // ---- z-gate ----
            h16x2 cz[4] = {h16x2{0,0}, h16x2{0,0}, h16x2{0,0}, h16x2{0,0}};
            #pragma unroll
            for (int i = 0; i < 32; ++i) cz[i >> 3] = wz[i] * hh[i] + cz[i >> 3];
            float sz = xpz;
            #pragma unroll
            for (int k = 0; k < 4; ++k) sz = fdot2(cz[k], ones, sz);
            float z  = __builtin_amdgcn_rcpf(1.0f + __builtin_amdgcn_exp2f(sz));

            // ---- n-gate ----
            h16x2 cn[4] = {h16x2{0,0}, h16x2{0,0}, h16x2{0,0}, h16x2{0,0}};
            #pragma unroll
            for (int i = 0; i < 32; ++i) cn[i >> 3] = wn[i] * hh[i] + cn[i >> 3];
            float hn = bhn;
            #pragma unroll
            for (int k = 0; k < 4; ++k) hn = fdot2(cn[k], ones, hn);
            float pre = fmaf(r, hn, xpn);
            float n   = fmaf(-2.0f, __builtin_amdgcn_rcpf(
                              1.0f + __builtin_amdgcn_exp2f(pre)), 1.0f);

            float h_new = fmaf(z, h_own - n, n);   // (1-z)*n + z*h
            h_own = h_new;

            // publish FIRST: next step's read turnaround starts now
            shh[lane] = (_Float16)h_new;

            // output: lane 63 stashes (exec-masked ds_write, off the path)
            if (lane == 63) obuf[t2] = h_new;
        }

        orow[tb * 64 + lane] = obuf[lane];         // coalesced 256B store
        xa = xb;
    }
}

extern "C" void kernel_launch(void* const* d_in, const int* in_sizes, int n_in,
                              void* d_out, int out_size, void* d_ws, size_t ws_size,
                              hipStream_t stream) {
    const float* x    = (const float*)d_in[0];
    const float* W_ih = (const float*)d_in[1];
    const float* W_hh = (const float*)d_in[2];
    const float* b_ih = (const float*)d_in[3];
    const float* b_hh = (const float*)d_in[4];
    float* out = (float*)d_out;

    dim3 grid(B_), block(64);
    gru_kernel<<<grid, block, 0, stream>>>(x, W_ih, W_hh, b_ih, b_hh, out);
}

// Round 18
// 612.557 us; speedup vs baseline: 1.1866x; 1.0350x over previous
//
#include <hip/hip_runtime.h>

#define B_ 256
#define T_ 2048
#define H_ 64

typedef float f32x4 __attribute__((ext_vector_type(4)));
typedef _Float16 h16x2 __attribute__((ext_vector_type(2)));

__device__ __forceinline__ float fdot2(h16x2 a, h16x2 b, float c) {
#if __has_builtin(__builtin_amdgcn_fdot2)
    return __builtin_amdgcn_fdot2(a, b, c, false);   // v_dot2_f32_f16
#else
    float d;
    asm("v_dot2_f32_f16 %0, %1, %2, %3" : "=v"(d) : "v"(a), "v"(b), "v"(c));
    return d;
#endif
}

__device__ __forceinline__ float readlane_f(float v, int idx) {
    return __builtin_bit_cast(float,
        __builtin_amdgcn_readlane(__builtin_bit_cast(int, v), idx));
}

#define NLOG2E (-1.4426950408889634f)   // -log2(e): sigmoid prescale
#define TLOG2E ( 2.8853900817779268f)   // 2*log2(e): tanh prescale

// FINAL KERNEL: exact restoration of R13 (best measured: 616 us across 17
// structurally distinct variants). Design, with the measured reasons:
//  - single wave per batch row, zero barriers (multi-wave sync costs
//    >=250 cyc/step: R1/R5/R6/R9);
//  - wall time = T x step-latency (strict recurrence); only the per-step
//    critical path matters;
//  - 192-MAC matvec costs ~384 VALU-issue cyc on one SIMD regardless of
//    primitive (dot2 / pk_fma_f16 / pk_fma_f32 / in-wave MFMA all ~0.5
//    MAC/cyc effective: R10/R12/R13/R15/R16);
//  - f16 prescaled weights (exp2 factors folded -> no mul at the head of
//    any transcendental chain), resident via one-time launder;
//  - gate pre-activations: 96 pk_fma_f16 chains + 12 fdot2 folds, gates
//    ordered r->z->n so each sigmoid's ~20cyc hides under the next gate's
//    dot issue;
//  - h exchange via 128-byte LDS broadcast image: 1 ds_write_b16 + 8
//    uniform-address ds_read_b128, conflict-free, published immediately
//    after h_new (register broadcast was worse: R14; LDS-stash output
//    latch was worse: R17);
//  - x distributed via readlane from a per-64-step coalesced load.
__global__ __launch_bounds__(64, 1)
void gru_kernel(const float* __restrict__ x,
                const float* __restrict__ W_ih,
                const float* __restrict__ W_hh,
                const float* __restrict__ b_ih,
                const float* __restrict__ b_hh,
                float* __restrict__ out)
{
#pragma clang fp contract(fast)
    __shared__ __align__(16) _Float16 shh[H_];

    const int lane = threadIdx.x;
    const int b    = blockIdx.x;

    // ---- preload W_hh rows {lane, 64+lane, 128+lane}, prescale, cvt f16 ----
    h16x2 wr[32], wz[32], wn[32];
    {
        const f32x4* pr = (const f32x4*)(W_hh + (size_t)lane * H_);
        const f32x4* pz = (const f32x4*)(W_hh + (size_t)(64 + lane) * H_);
        const f32x4* pn = (const f32x4*)(W_hh + (size_t)(128 + lane) * H_);
        #pragma unroll
        for (int q = 0; q < 16; ++q) {
            f32x4 vr = pr[q], vz = pz[q], vn = pn[q];
            wr[2*q]   = h16x2{(_Float16)(NLOG2E * vr.x), (_Float16)(NLOG2E * vr.y)};
            wr[2*q+1] = h16x2{(_Float16)(NLOG2E * vr.z), (_Float16)(NLOG2E * vr.w)};
            wz[2*q]   = h16x2{(_Float16)(NLOG2E * vz.x), (_Float16)(NLOG2E * vz.y)};
            wz[2*q+1] = h16x2{(_Float16)(NLOG2E * vz.z), (_Float16)(NLOG2E * vz.w)};
            wn[2*q]   = h16x2{(_Float16)(TLOG2E * vn.x), (_Float16)(TLOG2E * vn.y)};
            wn[2*q+1] = h16x2{(_Float16)(TLOG2E * vn.z), (_Float16)(TLOG2E * vn.w)};
        }
    }
    #pragma unroll
    for (int i = 0; i < 32; ++i)
        asm volatile("" : "+v"(wr[i]), "+v"(wz[i]), "+v"(wn[i]));

    // x-side params, prescaled
    const float wihr = NLOG2E * W_ih[lane];
    const float wihz = NLOG2E * W_ih[64 + lane];
    const float wihn = TLOG2E * W_ih[128 + lane];
    const float br   = NLOG2E * (b_ih[lane]      + b_hh[lane]);
    const float bz   = NLOG2E * (b_ih[64 + lane] + b_hh[64 + lane]);
    const float bhn  = TLOG2E * b_hh[128 + lane];
    const float bin  = TLOG2E * b_ih[128 + lane];

    const h16x2 ones = h16x2{(_Float16)1.0f, (_Float16)1.0f};

    const float* __restrict__ xrow = x + (size_t)b * T_;
    float* __restrict__ orow = out + (size_t)b * T_;

    shh[lane] = (_Float16)0.0f;      // h0 = 0 (single wave: in-order LDS)

    float h_own = 0.0f;
    float oval  = 0.0f;
    float xa = xrow[lane];           // current 64-step block of x
    float xb = 0.0f;

    for (int tb = 0; tb < T_ / 64; ++tb) {
        if (tb < T_ / 64 - 1) xb = xrow[(tb + 1) * 64 + lane];

        #pragma unroll 4
        for (int t2 = 0; t2 < 64; ++t2) {
            const float xt  = readlane_f(xa, t2);
            const float xpr = fmaf(xt, wihr, br);
            const float xpz = fmaf(xt, wihz, bz);
            const float xpn = fmaf(xt, wihn, bin);

            // ---- h: 8 broadcast ds_read_b128 (64 f16 = 128 B) ----
            h16x2 hh[32];
            const f32x4* hp = (const f32x4*)shh;
            #pragma unroll
            for (int q = 0; q < 8; ++q) {
                union { f32x4 f; h16x2 h[4]; } u;
                u.f = hp[q];
                hh[4*q]   = u.h[0];
                hh[4*q+1] = u.h[1];
                hh[4*q+2] = u.h[2];
                hh[4*q+3] = u.h[3];
            }

            // ---- r-gate: 32 pk_fma_f16 (4 chains of 8) + 4 fdot2 fold ----
            h16x2 cr[4] = {h16x2{0,0}, h16x2{0,0}, h16x2{0,0}, h16x2{0,0}};
            #pragma unroll
            for (int i = 0; i < 32; ++i) cr[i >> 3] = wr[i] * hh[i] + cr[i >> 3];
            float sr = xpr;
            #pragma unroll
            for (int k = 0; k < 4; ++k) sr = fdot2(cr[k], ones, sr);
            float r  = __builtin_amdgcn_rcpf(1.0f + __builtin_amdgcn_exp2f(sr));

            // ---- z-gate ----
            h16x2 cz[4] = {h16x2{0,0}, h16x2{0,0}, h16x2{0,0}, h16x2{0,0}};
            #pragma unroll
            for (int i = 0; i < 32; ++i) cz[i >> 3] = wz[i] * hh[i] + cz[i >> 3];
            float sz = xpz;
            #pragma unroll
            for (int k = 0; k < 4; ++k) sz = fdot2(cz[k], ones, sz);
            float z  = __builtin_amdgcn_rcpf(1.0f + __builtin_amdgcn_exp2f(sz));

            // ---- n-gate ----
            h16x2 cn[4] = {h16x2{0,0}, h16x2{0,0}, h16x2{0,0}, h16x2{0,0}};
            #pragma unroll
            for (int i = 0; i < 32; ++i) cn[i >> 3] = wn[i] * hh[i] + cn[i >> 3];
            float hn = bhn;
            #pragma unroll
            for (int k = 0; k < 4; ++k) hn = fdot2(cn[k], ones, hn);
            float pre = fmaf(r, hn, xpn);
            float n   = fmaf(-2.0f, __builtin_amdgcn_rcpf(
                              1.0f + __builtin_amdgcn_exp2f(pre)), 1.0f);

            float h_new = fmaf(z, h_own - n, n);   // (1-z)*n + z*h
            h_own = h_new;

            // publish FIRST: next step's read turnaround starts now
            shh[lane] = (_Float16)h_new;

            // output latch (off critical path)
            float h63 = readlane_f(h_new, 63);
            oval = (t2 == lane) ? h63 : oval;
        }

        orow[tb * 64 + lane] = oval;               // coalesced 256B store
        xa = xb;
    }
}

extern "C" void kernel_launch(void* const* d_in, const int* in_sizes, int n_in,
                              void* d_out, int out_size, void* d_ws, size_t ws_size,
                              hipStream_t stream) {
    const float* x    = (const float*)d_in[0];
    const float* W_ih = (const float*)d_in[1];
    const float* W_hh = (const float*)d_in[2];
    const float* b_ih = (const float*)d_in[3];
    const float* b_hh = (const float*)d_in[4];
    float* out = (float*)d_out;

    dim3 grid(B_), block(64);
    gru_kernel<<<grid, block, 0, stream>>>(x, W_ih, W_hh, b_ih, b_hh, out);
}